// Round 7
// baseline (817.229 us; speedup 1.0000x reference)
//
#include <hip/hip_runtime.h>
#include <hip/hip_bf16.h>
#include <math.h>

typedef __bf16 bf16x8 __attribute__((ext_vector_type(8)));
typedef float  f32x4  __attribute__((ext_vector_type(4)));

#define MFMA16 __builtin_amdgcn_mfma_f32_16x16x32_bf16

__device__ __forceinline__ float silu_f(float v) {
    return v * __builtin_amdgcn_rcpf(1.0f + __expf(-v));
}

// LDS weight layout: Wt[j][k], bf16, 16B-chunk XOR swizzle:
// phys = j*K + (((k>>3) ^ (j&7))<<3) + (k&7)  -> ds_read_b128, 2-way max.

// ---- detector: is edge_index stored as int64 (odd words all zero)? ---------
__global__ void k_detect(const int* __restrict__ ei, int* __restrict__ flag) {
    __shared__ int red[256];
    int v = 0;
#pragma unroll
    for (int j = 0; j < 4; ++j) v |= ei[2 * (threadIdx.x * 4 + j) + 1];
    red[threadIdx.x] = v;
    __syncthreads();
    for (int s = 128; s > 0; s >>= 1) {
        if (threadIdx.x < s) red[threadIdx.x] |= red[threadIdx.x + s];
        __syncthreads();
    }
    if (threadIdx.x == 0) *flag = (red[0] == 0) ? 1 : 0;
}

// ---- CSR build --------------------------------------------------------------
__global__ __launch_bounds__(256) void k_hist(
    const int* __restrict__ ei, const int* __restrict__ flag,
    int* __restrict__ counts, int E)
{
    int e = blockIdx.x * 256 + threadIdx.x;
    if (e >= E) return;
    const int is64 = *flag;
    int r = is64 ? ei[2 * E + 2 * e] : ei[E + e];
    atomicAdd(&counts[r], 1);
}

__global__ __launch_bounds__(256) void k_scan1(
    const int* __restrict__ counts, int* __restrict__ offsets,
    int* __restrict__ partials, int N)
{
    __shared__ int pairv[256];
    __shared__ int buf[256];
    const int t = threadIdx.x;
    const int base = blockIdx.x * 512;
    int a = (base + 2 * t     < N) ? counts[base + 2 * t]     : 0;
    int b = (base + 2 * t + 1 < N) ? counts[base + 2 * t + 1] : 0;
    pairv[t] = a + b;
    buf[t]   = a + b;
    __syncthreads();
    for (int d = 1; d < 256; d <<= 1) {
        int v = buf[t];
        int w = (t >= d) ? buf[t - d] : 0;
        __syncthreads();
        buf[t] = v + w;
        __syncthreads();
    }
    int excl = buf[t] - pairv[t];
    if (base + 2 * t     < N) offsets[base + 2 * t]     = excl;
    if (base + 2 * t + 1 < N) offsets[base + 2 * t + 1] = excl + a;
    if (t == 255) partials[blockIdx.x] = buf[255];
}

__global__ void k_scan2(int* __restrict__ partials, int nblk) {
    __shared__ int buf[256];
    const int t = threadIdx.x;
    int v0 = (t < nblk) ? partials[t] : 0;
    buf[t] = v0;
    __syncthreads();
    for (int d = 1; d < 256; d <<= 1) {
        int v = buf[t];
        int w = (t >= d) ? buf[t - d] : 0;
        __syncthreads();
        buf[t] = v + w;
        __syncthreads();
    }
    if (t < nblk) partials[t] = buf[t] - v0;   // exclusive
}

__global__ __launch_bounds__(256) void k_scan3(
    int* __restrict__ offsets, const int* __restrict__ partials,
    int* __restrict__ cursor, int N)
{
    int i = blockIdx.x * 256 + threadIdx.x;
    if (i >= N) return;
    int v = offsets[i] + partials[i >> 9];
    offsets[i] = v;
    cursor[i]  = v;
}

__global__ __launch_bounds__(256) void k_scatter(
    const int* __restrict__ ei, const int* __restrict__ flag,
    int* __restrict__ cursor, int2* __restrict__ csr_sr, int E)
{
    int e = blockIdx.x * 256 + threadIdx.x;
    if (e >= E) return;
    const int is64 = *flag;
    int s, r;
    if (is64) { s = ei[2 * e]; r = ei[2 * E + 2 * e]; }
    else      { s = ei[e];     r = ei[E + e];         }
    int slot = atomicAdd(&cursor[r], 1);
    csr_sr[slot] = make_int2(s, r);
}

// ---- phase 1: AB[n][0:128]=bf16(x@W1a + b1), AB[n][128:256]=bf16(x@W1b) ----
__global__ __launch_bounds__(256) void k_node1(
    const float* __restrict__ x, const float* __restrict__ W1,
    const float* __restrict__ b1, __bf16* __restrict__ AB, int N, int ngroups)
{
    __shared__ __bf16 wt[256 * 128];
    for (int idx = threadIdx.x; idx < 256 * 128; idx += 256) {
        int j = idx & 255, k = idx >> 8;
        float w = (j < 128) ? W1[(k << 7) + j] : W1[((k + 128) << 7) + (j - 128)];
        wt[(j << 7) + ((((k >> 3) ^ (j & 7))) << 3) + (k & 7)] = (__bf16)w;
    }
    __syncthreads();

    const int lane = threadIdx.x & 63;
    const int row  = lane & 15;
    const int kq   = lane >> 4;

    for (int g = blockIdx.x; g < ngroups; g += gridDim.x) {
        const int row0 = g * 64 + (threadIdx.x >> 6) * 16;
        int m = row0 + row; if (m >= N) m = N - 1;
        const float* xr = x + (size_t)m * 128;

        bf16x8 afr[4];
#pragma unroll
        for (int c = 0; c < 4; ++c) {
            const int k0 = c * 32 + kq * 8;
            float4 a0 = *(const float4*)(xr + k0);
            float4 a1 = *(const float4*)(xr + k0 + 4);
            bf16x8 af;
            af[0]=(__bf16)a0.x; af[1]=(__bf16)a0.y; af[2]=(__bf16)a0.z; af[3]=(__bf16)a0.w;
            af[4]=(__bf16)a1.x; af[5]=(__bf16)a1.y; af[6]=(__bf16)a1.z; af[7]=(__bf16)a1.w;
            afr[c] = af;
        }

        f32x4 acc[16] = {};
#pragma unroll
        for (int t = 0; t < 16; ++t) {
            const int j  = t * 16 + row;
            const int jb = j & 7;
            const __bf16* base = wt + (j << 7);
#pragma unroll
            for (int c = 0; c < 4; ++c) {
                const int kb = c * 4 + kq;
                bf16x8 b = *(const bf16x8*)(base + ((kb ^ jb) << 3));
                acc[t] = MFMA16(afr[c], b, acc[t], 0, 0, 0);
            }
        }

#pragma unroll
        for (int t = 0; t < 16; ++t) {
            const int col = t * 16 + row;
            const float bb = (col < 128) ? b1[col] : 0.0f;
#pragma unroll
            for (int q = 0; q < 4; ++q) {
                const int gr = row0 + kq * 4 + q;
                if (gr < N) AB[(size_t)gr * 256 + col] = (__bf16)(acc[t][q] + bb);
            }
        }
    }
}

// ---- phase 2: CSR-range blocks, LDS aggregation, zero global atomics -------
// Block b owns receivers [32b, 32b+32) and their contiguous sorted edge range.
// Messages accumulate into LDS f32 (ds_add), flushed once with plain stores.
// A/B gathers are software-pipelined into reused registers (no dup buffers).
#define RPB 32
__global__ __launch_bounds__(256) void k_edge_agg(
    const __bf16* __restrict__ AB, const float* __restrict__ pos,
    const int2* __restrict__ csr_sr, const int* __restrict__ offs,
    const float* __restrict__ W2, const float* __restrict__ b2,
    const float* __restrict__ w3, float* __restrict__ aggr, int N, int E)
{
    __shared__ __bf16 wt[128 * 128];     // 32 KB
    __shared__ float  agg[RPB * 128];    // 16 KB
    for (int idx = threadIdx.x; idx < 128 * 128; idx += 256) {
        int j = idx & 127, k = idx >> 7;
        wt[(j << 7) + ((((k >> 3) ^ (j & 7))) << 3) + (k & 7)] = (__bf16)W2[(k << 7) + j];
    }
    for (int i = threadIdx.x; i < RPB * 128; i += 256) agg[i] = 0.0f;
    __syncthreads();

    const int r0 = blockIdx.x * RPB;
    const int r1 = (r0 + RPB < N) ? (r0 + RPB) : N;
    const int e0 = offs[r0];
    const int e1 = (r1 < N) ? offs[r1] : E;

    const int lane = threadIdx.x & 63;
    const int row  = lane & 15;
    const int kq   = lane >> 4;
    const int wid  = threadIdx.x >> 6;

    float b2c[8];
#pragma unroll
    for (int t = 0; t < 8; ++t) b2c[t] = b2[t * 16 + row];

    const int ew0 = e0 + wid * 16;       // this wave's first edge slot
    if (ew0 < e1) {
        // ---- prologue: load current tile's (s,r), dist, A/B rows ----------
        int ec = ew0 + row; if (ec >= e1) ec = e1 - 1;
        int2 sr = csr_sr[ec];
        float d;
        {
            float dx = pos[3 * sr.x]     - pos[3 * sr.y];
            float dy = pos[3 * sr.x + 1] - pos[3 * sr.y + 1];
            float dz = pos[3 * sr.x + 2] - pos[3 * sr.y + 2];
            d = sqrtf(dx * dx + dy * dy + dz * dz);
        }
        bf16x8 av[4], bv[4];
#pragma unroll
        for (int c = 0; c < 4; ++c) {
            const int k0 = c * 32 + kq * 8;
            av[c] = *(const bf16x8*)(AB + (size_t)sr.x * 256 + k0);
            bv[c] = *(const bf16x8*)(AB + (size_t)sr.y * 256 + 128 + k0);
        }
        int en = ew0 + 64 + row; if (en >= e1) en = e1 - 1;
        int2 srn = csr_sr[en];

        for (int eb = ew0; eb < e1; eb += 64) {
            // ---- first layer: silu(A[s] + B[r] + d*w3) -> afr; frees av/bv
            bf16x8 afr[4];
#pragma unroll
            for (int c = 0; c < 4; ++c) {
                const int k0 = c * 32 + kq * 8;
                float4 w0 = *(const float4*)(w3 + k0);
                float4 w1 = *(const float4*)(w3 + k0 + 4);
                bf16x8 a = av[c], b = bv[c], af;
                af[0] = (__bf16)silu_f((float)a[0] + (float)b[0] + d * w0.x);
                af[1] = (__bf16)silu_f((float)a[1] + (float)b[1] + d * w0.y);
                af[2] = (__bf16)silu_f((float)a[2] + (float)b[2] + d * w0.z);
                af[3] = (__bf16)silu_f((float)a[3] + (float)b[3] + d * w0.w);
                af[4] = (__bf16)silu_f((float)a[4] + (float)b[4] + d * w1.x);
                af[5] = (__bf16)silu_f((float)a[5] + (float)b[5] + d * w1.y);
                af[6] = (__bf16)silu_f((float)a[6] + (float)b[6] + d * w1.z);
                af[7] = (__bf16)silu_f((float)a[7] + (float)b[7] + d * w1.w);
                afr[c] = af;
            }

            // receivers of the current tile (before sr is overwritten)
            int rr[4];
#pragma unroll
            for (int q = 0; q < 4; ++q) rr[q] = __shfl(sr.y, kq * 4 + q, 64);

            // ---- prefetch next tile into the SAME av/bv registers ---------
            float dn = 0.0f;
            {
                float dx = pos[3 * srn.x]     - pos[3 * srn.y];
                float dy = pos[3 * srn.x + 1] - pos[3 * srn.y + 1];
                float dz = pos[3 * srn.x + 2] - pos[3 * srn.y + 2];
                dn = sqrtf(dx * dx + dy * dy + dz * dz);
            }
#pragma unroll
            for (int c = 0; c < 4; ++c) {
                const int k0 = c * 32 + kq * 8;
                av[c] = *(const bf16x8*)(AB + (size_t)srn.x * 256 + k0);
                bv[c] = *(const bf16x8*)(AB + (size_t)srn.y * 256 + 128 + k0);
            }
            sr = srn;
            {
                int e2 = eb + 128 + row; if (e2 >= e1) e2 = e1 - 1;
                srn = csr_sr[e2];
            }
            d = dn;

            // ---- GEMM2 + silu + LDS-atomic accumulate (2 halves of 4 t) ---
#pragma unroll
            for (int th = 0; th < 2; ++th) {
                f32x4 acc[4] = {};
#pragma unroll
                for (int t4 = 0; t4 < 4; ++t4) {
                    const int j  = (th * 4 + t4) * 16 + row;
                    const int jb = j & 7;
                    const __bf16* base = wt + (j << 7);
#pragma unroll
                    for (int c = 0; c < 4; ++c) {
                        const int kb = c * 4 + kq;
                        bf16x8 b = *(const bf16x8*)(base + ((kb ^ jb) << 3));
                        acc[t4] = MFMA16(afr[c], b, acc[t4], 0, 0, 0);
                    }
                }
#pragma unroll
                for (int t4 = 0; t4 < 4; ++t4) {
                    const int t   = th * 4 + t4;
                    const int col = t * 16 + row;
#pragma unroll
                    for (int q = 0; q < 4; ++q) {
                        if (eb + kq * 4 + q < e1) {
                            float v = silu_f(acc[t4][q] + b2c[t]);
                            atomicAdd(&agg[(rr[q] - r0) * 128 + col], v);
                        }
                    }
                }
            }
        }
    }

    __syncthreads();
    // ---- flush: plain coalesced stores, rows wholly owned by this block ----
    for (int i = threadIdx.x * 4; i < RPB * 128; i += 256 * 4) {
        const int rr_ = r0 + (i >> 7);
        if (rr_ < N) *(float4*)(aggr + (size_t)rr_ * 128 + (i & 127)) =
                         *(const float4*)(agg + i);
    }
}

// ---- phase 2 fallback (round-3 atomic version, if ws too small) ------------
__global__ __launch_bounds__(256) void k_edge_fb(
    const __bf16* __restrict__ AB, const float* __restrict__ pos,
    const int* __restrict__ ei, const int* __restrict__ flag,
    const float* __restrict__ W2, const float* __restrict__ b2,
    const float* __restrict__ w3, float* __restrict__ aggr, int E, int ngroups)
{
    __shared__ __bf16 wt[128 * 128];
    for (int idx = threadIdx.x; idx < 128 * 128; idx += 256) {
        int j = idx & 127, k = idx >> 7;
        wt[(j << 7) + ((((k >> 3) ^ (j & 7))) << 3) + (k & 7)] = (__bf16)W2[(k << 7) + j];
    }
    __syncthreads();

    const int is64 = flag ? *flag : 0;
    const int lane = threadIdx.x & 63;
    const int row  = lane & 15;
    const int kq   = lane >> 4;

    for (int g = blockIdx.x; g < ngroups; g += gridDim.x) {
        const int e = g * 64 + (threadIdx.x >> 6) * 16 + row;
        int s, r;
        if (is64) { s = ei[2 * e]; r = ei[2 * E + 2 * e]; }
        else      { s = ei[e];     r = ei[E + e];         }
        float dx = pos[3 * s + 0] - pos[3 * r + 0];
        float dy = pos[3 * s + 1] - pos[3 * r + 1];
        float dz = pos[3 * s + 2] - pos[3 * r + 2];
        float d  = sqrtf(dx * dx + dy * dy + dz * dz);

        const __bf16* Arow = AB + (size_t)s * 256;
        const __bf16* Brow = AB + (size_t)r * 256 + 128;

        bf16x8 afr[4];
#pragma unroll
        for (int c = 0; c < 4; ++c) {
            const int k0 = c * 32 + kq * 8;
            bf16x8 av = *(const bf16x8*)(Arow + k0);
            bf16x8 bv = *(const bf16x8*)(Brow + k0);
            float4 w0 = *(const float4*)(w3 + k0);
            float4 w1 = *(const float4*)(w3 + k0 + 4);
            bf16x8 af;
            af[0] = (__bf16)silu_f((float)av[0] + (float)bv[0] + d * w0.x);
            af[1] = (__bf16)silu_f((float)av[1] + (float)bv[1] + d * w0.y);
            af[2] = (__bf16)silu_f((float)av[2] + (float)bv[2] + d * w0.z);
            af[3] = (__bf16)silu_f((float)av[3] + (float)bv[3] + d * w0.w);
            af[4] = (__bf16)silu_f((float)av[4] + (float)bv[4] + d * w1.x);
            af[5] = (__bf16)silu_f((float)av[5] + (float)bv[5] + d * w1.y);
            af[6] = (__bf16)silu_f((float)av[6] + (float)bv[6] + d * w1.z);
            af[7] = (__bf16)silu_f((float)av[7] + (float)bv[7] + d * w1.w);
            afr[c] = af;
        }

        f32x4 acc[8] = {};
#pragma unroll
        for (int t = 0; t < 8; ++t) {
            const int j  = t * 16 + row;
            const int jb = j & 7;
            const __bf16* base = wt + (j << 7);
#pragma unroll
            for (int c = 0; c < 4; ++c) {
                const int kb = c * 4 + kq;
                bf16x8 b = *(const bf16x8*)(base + ((kb ^ jb) << 3));
                acc[t] = MFMA16(afr[c], b, acc[t], 0, 0, 0);
            }
        }

        int rr[4];
#pragma unroll
        for (int q = 0; q < 4; ++q) rr[q] = __shfl(r, kq * 4 + q, 64);

#pragma unroll
        for (int t = 0; t < 8; ++t) {
            const int col = t * 16 + row;
            const float bb = b2[col];
#pragma unroll
            for (int q = 0; q < 4; ++q) {
                float v = silu_f(acc[t][q] + bb);
                unsafeAtomicAdd(aggr + (size_t)rr[q] * 128 + col, v);
            }
        }
    }
}

// -------- phase 3: u = silu(x@U1a + aggr@U1b + c1), bf16, IN PLACE over aggr
__global__ __launch_bounds__(256) void k_node2(
    const float* __restrict__ x, const float* __restrict__ aggr,
    const float* __restrict__ U1, const float* __restrict__ c1,
    __bf16* __restrict__ u, int N, int ngroups)
{
    __shared__ __bf16 wt[128 * 256];
    for (int idx = threadIdx.x; idx < 128 * 256; idx += 256) {
        int j = idx & 127, k = idx >> 7;
        wt[(j << 8) + ((((k >> 3) ^ (j & 7))) << 3) + (k & 7)] = (__bf16)U1[(k << 7) + j];
    }
    __syncthreads();

    const int lane = threadIdx.x & 63;
    const int row  = lane & 15;
    const int kq   = lane >> 4;

    for (int g = blockIdx.x; g < ngroups; g += gridDim.x) {
        const int row0 = g * 64 + (threadIdx.x >> 6) * 16;
        int m = row0 + row; if (m >= N) m = N - 1;

        bf16x8 afr[8];
#pragma unroll
        for (int c = 0; c < 8; ++c) {
            const int k0 = (c & 3) * 32 + kq * 8;
            const float* src = (c < 4) ? (x + (size_t)m * 128 + k0)
                                       : (aggr + (size_t)m * 128 + k0);
            float4 a0 = *(const float4*)(src);
            float4 a1 = *(const float4*)(src + 4);
            bf16x8 af;
            af[0]=(__bf16)a0.x; af[1]=(__bf16)a0.y; af[2]=(__bf16)a0.z; af[3]=(__bf16)a0.w;
            af[4]=(__bf16)a1.x; af[5]=(__bf16)a1.y; af[6]=(__bf16)a1.z; af[7]=(__bf16)a1.w;
            afr[c] = af;
        }

        f32x4 acc[8] = {};
#pragma unroll
        for (int t = 0; t < 8; ++t) {
            const int j  = t * 16 + row;
            const int jb = j & 7;
            const __bf16* base = wt + (j << 8);
#pragma unroll
            for (int c = 0; c < 8; ++c) {
                const int kb = c * 4 + kq;
                bf16x8 b = *(const bf16x8*)(base + ((kb ^ jb) << 3));
                acc[t] = MFMA16(afr[c], b, acc[t], 0, 0, 0);
            }
        }

#pragma unroll
        for (int t = 0; t < 8; ++t) {
            const int col = t * 16 + row;
            const float cc = c1[col];
#pragma unroll
            for (int q = 0; q < 4; ++q) {
                const int gr = row0 + kq * 4 + q;
                if (gr < N) u[(size_t)gr * 256 + col] = (__bf16)silu_f(acc[t][q] + cc);
            }
        }
    }
}

// ---------------- phase 4: out = u@U2 + c2 (overwrites AB in d_out) ---------
__global__ __launch_bounds__(256) void k_node3(
    const __bf16* __restrict__ u, const float* __restrict__ U2,
    const float* __restrict__ c2, float* __restrict__ out, int N, int ngroups)
{
    __shared__ __bf16 wt[128 * 128];
    for (int idx = threadIdx.x; idx < 128 * 128; idx += 256) {
        int j = idx & 127, k = idx >> 7;
        wt[(j << 7) + ((((k >> 3) ^ (j & 7))) << 3) + (k & 7)] = (__bf16)U2[(k << 7) + j];
    }
    __syncthreads();

    const int lane = threadIdx.x & 63;
    const int row  = lane & 15;
    const int kq   = lane >> 4;

    for (int g = blockIdx.x; g < ngroups; g += gridDim.x) {
        const int row0 = g * 64 + (threadIdx.x >> 6) * 16;
        int m = row0 + row; if (m >= N) m = N - 1;

        bf16x8 afr[4];
#pragma unroll
        for (int c = 0; c < 4; ++c) {
            const int k0 = c * 32 + kq * 8;
            afr[c] = *(const bf16x8*)(u + (size_t)m * 256 + k0);
        }

        f32x4 acc[8] = {};
#pragma unroll
        for (int t = 0; t < 8; ++t) {
            const int j  = t * 16 + row;
            const int jb = j & 7;
            const __bf16* base = wt + (j << 7);
#pragma unroll
            for (int c = 0; c < 4; ++c) {
                const int kb = c * 4 + kq;
                bf16x8 b = *(const bf16x8*)(base + ((kb ^ jb) << 3));
                acc[t] = MFMA16(afr[c], b, acc[t], 0, 0, 0);
            }
        }

#pragma unroll
        for (int t = 0; t < 8; ++t) {
            const int col = t * 16 + row;
            const float cc = c2[col];
#pragma unroll
            for (int q = 0; q < 4; ++q) {
                const int gr = row0 + kq * 4 + q;
                if (gr < N) out[(size_t)gr * 128 + col] = acc[t][q] + cc;
            }
        }
    }
}

extern "C" void kernel_launch(void* const* d_in, const int* in_sizes, int n_in,
                              void* d_out, int out_size, void* d_ws, size_t ws_size,
                              hipStream_t stream) {
    (void)n_in; (void)out_size;
    const float* x   = (const float*)d_in[0];
    const float* pos = (const float*)d_in[1];
    const int*   ei  = (const int*)d_in[2];
    const float* W1  = (const float*)d_in[3];
    const float* b1  = (const float*)d_in[4];
    const float* W2  = (const float*)d_in[5];
    const float* b2  = (const float*)d_in[6];
    const float* U1  = (const float*)d_in[7];
    const float* c1  = (const float*)d_in[8];
    const float* U2  = (const float*)d_in[9];
    const float* c2  = (const float*)d_in[10];

    const int N = in_sizes[0] / 128;
    const int E = in_sizes[2] / 2;

    // ---- workspace layout (16B-aligned slabs) ----
    const size_t aggr_b  = (size_t)N * 128 * sizeof(float);
    const size_t Ni_b    = (((size_t)N * 4) + 15) & ~(size_t)15;
    const size_t E2_b    = (((size_t)E * 8) + 15) & ~(size_t)15;
    size_t off = 0;
    char* base = (char*)d_ws;
    float* aggr   = (float*)(base + off); off += aggr_b;
    int*   flag   = (int*)  (base + off); off += 16;
    int*   counts = (int*)  (base + off); off += Ni_b;
    int*   offs   = (int*)  (base + off); off += Ni_b;
    int*   cursor = (int*)  (base + off); off += Ni_b;
    int*   parts  = (int*)  (base + off); off += 256 * 4;
    int2*  csr_sr = (int2*) (base + off); off += E2_b;
    const size_t need_csr = off;

    __bf16* u  = (__bf16*)d_ws;        // row stride 256 elem, aliases aggr
    __bf16* AB = (__bf16*)d_out;       // N*256 bf16 == out_nbytes

    const int nblk_scan = (N + 511) / 512;
    const bool csr_ok = (ws_size >= need_csr) && (nblk_scan <= 256);

    if (ws_size < aggr_b + 16) return;   // cannot run at all

    const int ng_nodes = (N + 63) / 64;
    const int grid_n   = ng_nodes < 512 ? ng_nodes : 512;
    const int grid_E   = (E + 255) / 256;
    const int grid_Nt  = (N + 255) / 256;

    k_detect<<<1, 256, 0, stream>>>(ei, flag);
    k_node1<<<grid_n, 256, 0, stream>>>(x, W1, b1, AB, N, ng_nodes);

    if (csr_ok) {
        hipMemsetAsync(counts, 0, (size_t)N * 4, stream);
        k_hist   <<<grid_E, 256, 0, stream>>>(ei, flag, counts, E);
        k_scan1  <<<nblk_scan, 256, 0, stream>>>(counts, offs, parts, N);
        k_scan2  <<<1, 256, 0, stream>>>(parts, nblk_scan);
        k_scan3  <<<grid_Nt, 256, 0, stream>>>(offs, parts, cursor, N);
        k_scatter<<<grid_E, 256, 0, stream>>>(ei, flag, cursor, csr_sr, E);
        k_edge_agg<<<(N + RPB - 1) / RPB, 256, 0, stream>>>(
            AB, pos, csr_sr, offs, W2, b2, W1 + 256 * 128, aggr, N, E);
    } else {
        hipMemsetAsync(aggr, 0, aggr_b, stream);
        const int ng_edges = E / 64;
        const int grid_e   = ng_edges < 1250 ? ng_edges : 1250;
        k_edge_fb<<<grid_e, 256, 0, stream>>>(AB, pos, ei, flag, W2, b2,
                                              W1 + 256 * 128, aggr, E, ng_edges);
    }

    k_node2<<<grid_n, 256, 0, stream>>>(x, aggr, U1, c1, u, N, ng_nodes);
    k_node3<<<grid_n, 256, 0, stream>>>(u, U2, c2, (float*)d_out, N, ng_nodes);
}

// Round 8
// 521.798 us; speedup vs baseline: 1.5662x; 1.5662x over previous
//
#include <hip/hip_runtime.h>
#include <hip/hip_bf16.h>
#include <math.h>

typedef __bf16 bf16x8 __attribute__((ext_vector_type(8)));
typedef float  f32x4  __attribute__((ext_vector_type(4)));

#define MFMA16 __builtin_amdgcn_mfma_f32_16x16x32_bf16

__device__ __forceinline__ float silu_f(float v) {
    return v * __builtin_amdgcn_rcpf(1.0f + __expf(-v));
}

// LDS weight layout: Wt[j][k], bf16, 16B-chunk XOR swizzle:
// phys = j*K + (((k>>3) ^ (j&7))<<3) + (k&7)  -> ds_read_b128, 2-way max.

// ---- detector: is edge_index stored as int64 (odd words all zero)? ---------
__global__ void k_detect(const int* __restrict__ ei, int* __restrict__ flag) {
    __shared__ int red[256];
    int v = 0;
#pragma unroll
    for (int j = 0; j < 4; ++j) v |= ei[2 * (threadIdx.x * 4 + j) + 1];
    red[threadIdx.x] = v;
    __syncthreads();
    for (int s = 128; s > 0; s >>= 1) {
        if (threadIdx.x < s) red[threadIdx.x] |= red[threadIdx.x + s];
        __syncthreads();
    }
    if (threadIdx.x == 0) *flag = (red[0] == 0) ? 1 : 0;
}

// ---- CSR build --------------------------------------------------------------
__global__ __launch_bounds__(256) void k_hist(
    const int* __restrict__ ei, const int* __restrict__ flag,
    int* __restrict__ counts, int E)
{
    int e = blockIdx.x * 256 + threadIdx.x;
    if (e >= E) return;
    const int is64 = *flag;
    int r = is64 ? ei[2 * E + 2 * e] : ei[E + e];
    atomicAdd(&counts[r], 1);
}

__global__ __launch_bounds__(256) void k_scan1(
    const int* __restrict__ counts, int* __restrict__ offsets,
    int* __restrict__ partials, int N)
{
    __shared__ int pairv[256];
    __shared__ int buf[256];
    const int t = threadIdx.x;
    const int base = blockIdx.x * 512;
    int a = (base + 2 * t     < N) ? counts[base + 2 * t]     : 0;
    int b = (base + 2 * t + 1 < N) ? counts[base + 2 * t + 1] : 0;
    pairv[t] = a + b;
    buf[t]   = a + b;
    __syncthreads();
    for (int d = 1; d < 256; d <<= 1) {
        int v = buf[t];
        int w = (t >= d) ? buf[t - d] : 0;
        __syncthreads();
        buf[t] = v + w;
        __syncthreads();
    }
    int excl = buf[t] - pairv[t];
    if (base + 2 * t     < N) offsets[base + 2 * t]     = excl;
    if (base + 2 * t + 1 < N) offsets[base + 2 * t + 1] = excl + a;
    if (t == 255) partials[blockIdx.x] = buf[255];
}

__global__ void k_scan2(int* __restrict__ partials, int nblk) {
    __shared__ int buf[256];
    const int t = threadIdx.x;
    int v0 = (t < nblk) ? partials[t] : 0;
    buf[t] = v0;
    __syncthreads();
    for (int d = 1; d < 256; d <<= 1) {
        int v = buf[t];
        int w = (t >= d) ? buf[t - d] : 0;
        __syncthreads();
        buf[t] = v + w;
        __syncthreads();
    }
    if (t < nblk) partials[t] = buf[t] - v0;   // exclusive
}

__global__ __launch_bounds__(256) void k_scan3(
    int* __restrict__ offsets, const int* __restrict__ partials,
    int* __restrict__ cursor, int N)
{
    int i = blockIdx.x * 256 + threadIdx.x;
    if (i >= N) return;
    int v = offsets[i] + partials[i >> 9];
    offsets[i] = v;
    cursor[i]  = v;
}

__global__ __launch_bounds__(256) void k_scatter(
    const int* __restrict__ ei, const int* __restrict__ flag,
    int* __restrict__ cursor, int2* __restrict__ csr_sr, int E)
{
    int e = blockIdx.x * 256 + threadIdx.x;
    if (e >= E) return;
    const int is64 = *flag;
    int s, r;
    if (is64) { s = ei[2 * e]; r = ei[2 * E + 2 * e]; }
    else      { s = ei[e];     r = ei[E + e];         }
    int slot = atomicAdd(&cursor[r], 1);
    csr_sr[slot] = make_int2(s, r);
}

// ---- phase 1: AB[n][0:128]=bf16(x@W1a + b1), AB[n][128:256]=bf16(x@W1b) ----
__global__ __launch_bounds__(256) void k_node1(
    const float* __restrict__ x, const float* __restrict__ W1,
    const float* __restrict__ b1, __bf16* __restrict__ AB, int N, int ngroups)
{
    __shared__ __bf16 wt[256 * 128];
    for (int idx = threadIdx.x; idx < 256 * 128; idx += 256) {
        int j = idx & 255, k = idx >> 8;
        float w = (j < 128) ? W1[(k << 7) + j] : W1[((k + 128) << 7) + (j - 128)];
        wt[(j << 7) + ((((k >> 3) ^ (j & 7))) << 3) + (k & 7)] = (__bf16)w;
    }
    __syncthreads();

    const int lane = threadIdx.x & 63;
    const int row  = lane & 15;
    const int kq   = lane >> 4;

    for (int g = blockIdx.x; g < ngroups; g += gridDim.x) {
        const int row0 = g * 64 + (threadIdx.x >> 6) * 16;
        int m = row0 + row; if (m >= N) m = N - 1;
        const float* xr = x + (size_t)m * 128;

        bf16x8 afr[4];
#pragma unroll
        for (int c = 0; c < 4; ++c) {
            const int k0 = c * 32 + kq * 8;
            float4 a0 = *(const float4*)(xr + k0);
            float4 a1 = *(const float4*)(xr + k0 + 4);
            bf16x8 af;
            af[0]=(__bf16)a0.x; af[1]=(__bf16)a0.y; af[2]=(__bf16)a0.z; af[3]=(__bf16)a0.w;
            af[4]=(__bf16)a1.x; af[5]=(__bf16)a1.y; af[6]=(__bf16)a1.z; af[7]=(__bf16)a1.w;
            afr[c] = af;
        }

        f32x4 acc[16] = {};
#pragma unroll
        for (int t = 0; t < 16; ++t) {
            const int j  = t * 16 + row;
            const int jb = j & 7;
            const __bf16* base = wt + (j << 7);
#pragma unroll
            for (int c = 0; c < 4; ++c) {
                const int kb = c * 4 + kq;
                bf16x8 b = *(const bf16x8*)(base + ((kb ^ jb) << 3));
                acc[t] = MFMA16(afr[c], b, acc[t], 0, 0, 0);
            }
        }

#pragma unroll
        for (int t = 0; t < 16; ++t) {
            const int col = t * 16 + row;
            const float bb = (col < 128) ? b1[col] : 0.0f;
#pragma unroll
            for (int q = 0; q < 4; ++q) {
                const int gr = row0 + kq * 4 + q;
                if (gr < N) AB[(size_t)gr * 256 + col] = (__bf16)(acc[t][q] + bb);
            }
        }
    }
}

// ---- phase 2: edge-parallel, CSR-sorted, in-place run-merged atomics -------
// Same register budget as r3 (116 VGPR): silu in place into acc, forward
// merge across each lane's 4 sorted edges, atomic only at run boundaries.
__global__ __launch_bounds__(256) void k_edge_srt(
    const __bf16* __restrict__ AB, const float* __restrict__ pos,
    const int2* __restrict__ csr_sr,
    const float* __restrict__ W2, const float* __restrict__ b2,
    const float* __restrict__ w3, float* __restrict__ aggr, int E, int ngroups)
{
    __shared__ __bf16 wt[128 * 128];
    for (int idx = threadIdx.x; idx < 128 * 128; idx += 256) {
        int j = idx & 127, k = idx >> 7;
        wt[(j << 7) + ((((k >> 3) ^ (j & 7))) << 3) + (k & 7)] = (__bf16)W2[(k << 7) + j];
    }
    __syncthreads();

    const int lane = threadIdx.x & 63;
    const int row  = lane & 15;
    const int kq   = lane >> 4;

    float b2c[8];
#pragma unroll
    for (int t = 0; t < 8; ++t) b2c[t] = b2[t * 16 + row];

    for (int g = blockIdx.x; g < ngroups; g += gridDim.x) {
        const int e = g * 64 + (threadIdx.x >> 6) * 16 + row;
        const int2 sr = csr_sr[e];
        const int s = sr.x, r = sr.y;

        float dx = pos[3 * s + 0] - pos[3 * r + 0];
        float dy = pos[3 * s + 1] - pos[3 * r + 1];
        float dz = pos[3 * s + 2] - pos[3 * r + 2];
        float d  = sqrtf(dx * dx + dy * dy + dz * dz);

        const __bf16* Arow = AB + (size_t)s * 256;
        const __bf16* Brow = AB + (size_t)r * 256 + 128;

        bf16x8 afr[4];
#pragma unroll
        for (int c = 0; c < 4; ++c) {
            const int k0 = c * 32 + kq * 8;
            bf16x8 av = *(const bf16x8*)(Arow + k0);
            bf16x8 bv = *(const bf16x8*)(Brow + k0);
            float4 w0 = *(const float4*)(w3 + k0);
            float4 w1 = *(const float4*)(w3 + k0 + 4);
            bf16x8 af;
            af[0] = (__bf16)silu_f((float)av[0] + (float)bv[0] + d * w0.x);
            af[1] = (__bf16)silu_f((float)av[1] + (float)bv[1] + d * w0.y);
            af[2] = (__bf16)silu_f((float)av[2] + (float)bv[2] + d * w0.z);
            af[3] = (__bf16)silu_f((float)av[3] + (float)bv[3] + d * w0.w);
            af[4] = (__bf16)silu_f((float)av[4] + (float)bv[4] + d * w1.x);
            af[5] = (__bf16)silu_f((float)av[5] + (float)bv[5] + d * w1.y);
            af[6] = (__bf16)silu_f((float)av[6] + (float)bv[6] + d * w1.z);
            af[7] = (__bf16)silu_f((float)av[7] + (float)bv[7] + d * w1.w);
            afr[c] = af;
        }

        f32x4 acc[8] = {};
#pragma unroll
        for (int t = 0; t < 8; ++t) {
            const int j  = t * 16 + row;
            const int jb = j & 7;
            const __bf16* base = wt + (j << 7);
#pragma unroll
            for (int c = 0; c < 4; ++c) {
                const int kb = c * 4 + kq;
                bf16x8 b = *(const bf16x8*)(base + ((kb ^ jb) << 3));
                acc[t] = MFMA16(afr[c], b, acc[t], 0, 0, 0);
            }
        }

        // receivers of this lane's 4 consecutive sorted edges (er = kq*4+q)
        int rr[4];
#pragma unroll
        for (int q = 0; q < 4; ++q) rr[q] = __shfl(r, kq * 4 + q, 64);

        // run structure is t-invariant: merge/flush predicates computed once
        const bool mg0 = (rr[0] == rr[1]);
        const bool mg1 = (rr[1] == rr[2]);
        const bool mg2 = (rr[2] == rr[3]);

#pragma unroll
        for (int t = 0; t < 8; ++t) {
            const int col = t * 16 + row;
            // silu in place
#pragma unroll
            for (int q = 0; q < 4; ++q)
                acc[t][q] = silu_f(acc[t][q] + b2c[t]);
            // forward in-place merge of equal-receiver runs
            if (mg0) acc[t][1] += acc[t][0];
            if (mg1) acc[t][2] += acc[t][1];
            if (mg2) acc[t][3] += acc[t][2];
            // flush run tails only
            if (!mg0) unsafeAtomicAdd(aggr + (size_t)rr[0] * 128 + col, acc[t][0]);
            if (!mg1) unsafeAtomicAdd(aggr + (size_t)rr[1] * 128 + col, acc[t][1]);
            if (!mg2) unsafeAtomicAdd(aggr + (size_t)rr[2] * 128 + col, acc[t][2]);
            unsafeAtomicAdd(aggr + (size_t)rr[3] * 128 + col, acc[t][3]);
        }
    }
}

// ---- phase 2 fallback (round-3 atomic version, if ws too small) ------------
__global__ __launch_bounds__(256) void k_edge_fb(
    const __bf16* __restrict__ AB, const float* __restrict__ pos,
    const int* __restrict__ ei, const int* __restrict__ flag,
    const float* __restrict__ W2, const float* __restrict__ b2,
    const float* __restrict__ w3, float* __restrict__ aggr, int E, int ngroups)
{
    __shared__ __bf16 wt[128 * 128];
    for (int idx = threadIdx.x; idx < 128 * 128; idx += 256) {
        int j = idx & 127, k = idx >> 7;
        wt[(j << 7) + ((((k >> 3) ^ (j & 7))) << 3) + (k & 7)] = (__bf16)W2[(k << 7) + j];
    }
    __syncthreads();

    const int is64 = flag ? *flag : 0;
    const int lane = threadIdx.x & 63;
    const int row  = lane & 15;
    const int kq   = lane >> 4;

    for (int g = blockIdx.x; g < ngroups; g += gridDim.x) {
        const int e = g * 64 + (threadIdx.x >> 6) * 16 + row;
        int s, r;
        if (is64) { s = ei[2 * e]; r = ei[2 * E + 2 * e]; }
        else      { s = ei[e];     r = ei[E + e];         }
        float dx = pos[3 * s + 0] - pos[3 * r + 0];
        float dy = pos[3 * s + 1] - pos[3 * r + 1];
        float dz = pos[3 * s + 2] - pos[3 * r + 2];
        float d  = sqrtf(dx * dx + dy * dy + dz * dz);

        const __bf16* Arow = AB + (size_t)s * 256;
        const __bf16* Brow = AB + (size_t)r * 256 + 128;

        bf16x8 afr[4];
#pragma unroll
        for (int c = 0; c < 4; ++c) {
            const int k0 = c * 32 + kq * 8;
            bf16x8 av = *(const bf16x8*)(Arow + k0);
            bf16x8 bv = *(const bf16x8*)(Brow + k0);
            float4 w0 = *(const float4*)(w3 + k0);
            float4 w1 = *(const float4*)(w3 + k0 + 4);
            bf16x8 af;
            af[0] = (__bf16)silu_f((float)av[0] + (float)bv[0] + d * w0.x);
            af[1] = (__bf16)silu_f((float)av[1] + (float)bv[1] + d * w0.y);
            af[2] = (__bf16)silu_f((float)av[2] + (float)bv[2] + d * w0.z);
            af[3] = (__bf16)silu_f((float)av[3] + (float)bv[3] + d * w0.w);
            af[4] = (__bf16)silu_f((float)av[4] + (float)bv[4] + d * w1.x);
            af[5] = (__bf16)silu_f((float)av[5] + (float)bv[5] + d * w1.y);
            af[6] = (__bf16)silu_f((float)av[6] + (float)bv[6] + d * w1.z);
            af[7] = (__bf16)silu_f((float)av[7] + (float)bv[7] + d * w1.w);
            afr[c] = af;
        }

        f32x4 acc[8] = {};
#pragma unroll
        for (int t = 0; t < 8; ++t) {
            const int j  = t * 16 + row;
            const int jb = j & 7;
            const __bf16* base = wt + (j << 7);
#pragma unroll
            for (int c = 0; c < 4; ++c) {
                const int kb = c * 4 + kq;
                bf16x8 b = *(const bf16x8*)(base + ((kb ^ jb) << 3));
                acc[t] = MFMA16(afr[c], b, acc[t], 0, 0, 0);
            }
        }

        int rr[4];
#pragma unroll
        for (int q = 0; q < 4; ++q) rr[q] = __shfl(r, kq * 4 + q, 64);

#pragma unroll
        for (int t = 0; t < 8; ++t) {
            const int col = t * 16 + row;
            const float bb = b2[col];
#pragma unroll
            for (int q = 0; q < 4; ++q) {
                float v = silu_f(acc[t][q] + bb);
                unsafeAtomicAdd(aggr + (size_t)rr[q] * 128 + col, v);
            }
        }
    }
}

// -------- phase 3: u = silu(x@U1a + aggr@U1b + c1), bf16, IN PLACE over aggr
__global__ __launch_bounds__(256) void k_node2(
    const float* __restrict__ x, const float* __restrict__ aggr,
    const float* __restrict__ U1, const float* __restrict__ c1,
    __bf16* __restrict__ u, int N, int ngroups)
{
    __shared__ __bf16 wt[128 * 256];
    for (int idx = threadIdx.x; idx < 128 * 256; idx += 256) {
        int j = idx & 127, k = idx >> 7;
        wt[(j << 8) + ((((k >> 3) ^ (j & 7))) << 3) + (k & 7)] = (__bf16)U1[(k << 7) + j];
    }
    __syncthreads();

    const int lane = threadIdx.x & 63;
    const int row  = lane & 15;
    const int kq   = lane >> 4;

    for (int g = blockIdx.x; g < ngroups; g += gridDim.x) {
        const int row0 = g * 64 + (threadIdx.x >> 6) * 16;
        int m = row0 + row; if (m >= N) m = N - 1;

        bf16x8 afr[8];
#pragma unroll
        for (int c = 0; c < 8; ++c) {
            const int k0 = (c & 3) * 32 + kq * 8;
            const float* src = (c < 4) ? (x + (size_t)m * 128 + k0)
                                       : (aggr + (size_t)m * 128 + k0);
            float4 a0 = *(const float4*)(src);
            float4 a1 = *(const float4*)(src + 4);
            bf16x8 af;
            af[0]=(__bf16)a0.x; af[1]=(__bf16)a0.y; af[2]=(__bf16)a0.z; af[3]=(__bf16)a0.w;
            af[4]=(__bf16)a1.x; af[5]=(__bf16)a1.y; af[6]=(__bf16)a1.z; af[7]=(__bf16)a1.w;
            afr[c] = af;
        }

        f32x4 acc[8] = {};
#pragma unroll
        for (int t = 0; t < 8; ++t) {
            const int j  = t * 16 + row;
            const int jb = j & 7;
            const __bf16* base = wt + (j << 8);
#pragma unroll
            for (int c = 0; c < 8; ++c) {
                const int kb = c * 4 + kq;
                bf16x8 b = *(const bf16x8*)(base + ((kb ^ jb) << 3));
                acc[t] = MFMA16(afr[c], b, acc[t], 0, 0, 0);
            }
        }

#pragma unroll
        for (int t = 0; t < 8; ++t) {
            const int col = t * 16 + row;
            const float cc = c1[col];
#pragma unroll
            for (int q = 0; q < 4; ++q) {
                const int gr = row0 + kq * 4 + q;
                if (gr < N) u[(size_t)gr * 256 + col] = (__bf16)silu_f(acc[t][q] + cc);
            }
        }
    }
}

// ---------------- phase 4: out = u@U2 + c2 (overwrites AB in d_out) ---------
__global__ __launch_bounds__(256) void k_node3(
    const __bf16* __restrict__ u, const float* __restrict__ U2,
    const float* __restrict__ c2, float* __restrict__ out, int N, int ngroups)
{
    __shared__ __bf16 wt[128 * 128];
    for (int idx = threadIdx.x; idx < 128 * 128; idx += 256) {
        int j = idx & 127, k = idx >> 7;
        wt[(j << 7) + ((((k >> 3) ^ (j & 7))) << 3) + (k & 7)] = (__bf16)U2[(k << 7) + j];
    }
    __syncthreads();

    const int lane = threadIdx.x & 63;
    const int row  = lane & 15;
    const int kq   = lane >> 4;

    for (int g = blockIdx.x; g < ngroups; g += gridDim.x) {
        const int row0 = g * 64 + (threadIdx.x >> 6) * 16;
        int m = row0 + row; if (m >= N) m = N - 1;

        bf16x8 afr[4];
#pragma unroll
        for (int c = 0; c < 4; ++c) {
            const int k0 = c * 32 + kq * 8;
            afr[c] = *(const bf16x8*)(u + (size_t)m * 256 + k0);
        }

        f32x4 acc[8] = {};
#pragma unroll
        for (int t = 0; t < 8; ++t) {
            const int j  = t * 16 + row;
            const int jb = j & 7;
            const __bf16* base = wt + (j << 7);
#pragma unroll
            for (int c = 0; c < 4; ++c) {
                const int kb = c * 4 + kq;
                bf16x8 b = *(const bf16x8*)(base + ((kb ^ jb) << 3));
                acc[t] = MFMA16(afr[c], b, acc[t], 0, 0, 0);
            }
        }

#pragma unroll
        for (int t = 0; t < 8; ++t) {
            const int col = t * 16 + row;
            const float cc = c2[col];
#pragma unroll
            for (int q = 0; q < 4; ++q) {
                const int gr = row0 + kq * 4 + q;
                if (gr < N) out[(size_t)gr * 128 + col] = acc[t][q] + cc;
            }
        }
    }
}

extern "C" void kernel_launch(void* const* d_in, const int* in_sizes, int n_in,
                              void* d_out, int out_size, void* d_ws, size_t ws_size,
                              hipStream_t stream) {
    (void)n_in; (void)out_size;
    const float* x   = (const float*)d_in[0];
    const float* pos = (const float*)d_in[1];
    const int*   ei  = (const int*)d_in[2];
    const float* W1  = (const float*)d_in[3];
    const float* b1  = (const float*)d_in[4];
    const float* W2  = (const float*)d_in[5];
    const float* b2  = (const float*)d_in[6];
    const float* U1  = (const float*)d_in[7];
    const float* c1  = (const float*)d_in[8];
    const float* U2  = (const float*)d_in[9];
    const float* c2  = (const float*)d_in[10];

    const int N = in_sizes[0] / 128;
    const int E = in_sizes[2] / 2;

    // ---- workspace layout (16B-aligned slabs) ----
    const size_t aggr_b  = (size_t)N * 128 * sizeof(float);
    const size_t Ni_b    = (((size_t)N * 4) + 15) & ~(size_t)15;
    const size_t E2_b    = (((size_t)E * 8) + 15) & ~(size_t)15;
    size_t off = 0;
    char* base = (char*)d_ws;
    float* aggr   = (float*)(base + off); off += aggr_b;
    int*   flag   = (int*)  (base + off); off += 16;
    int*   counts = (int*)  (base + off); off += Ni_b;
    int*   offs   = (int*)  (base + off); off += Ni_b;
    int*   cursor = (int*)  (base + off); off += Ni_b;
    int*   parts  = (int*)  (base + off); off += 256 * 4;
    int2*  csr_sr = (int2*) (base + off); off += E2_b;
    const size_t need_csr = off;

    __bf16* u  = (__bf16*)d_ws;        // row stride 256 elem, aliases aggr
    __bf16* AB = (__bf16*)d_out;       // N*256 bf16 == out_nbytes

    const int nblk_scan = (N + 511) / 512;
    const bool csr_ok = (ws_size >= need_csr) && (nblk_scan <= 256);

    if (ws_size < aggr_b + 16) return;   // cannot run at all

    const int ng_nodes = (N + 63) / 64;
    const int grid_n   = ng_nodes < 512 ? ng_nodes : 512;
    const int grid_E   = (E + 255) / 256;
    const int grid_Nt  = (N + 255) / 256;
    const int ng_edges = E / 64;
    const int grid_e   = ng_edges < 1250 ? ng_edges : 1250;

    k_detect<<<1, 256, 0, stream>>>(ei, flag);
    k_node1<<<grid_n, 256, 0, stream>>>(x, W1, b1, AB, N, ng_nodes);
    hipMemsetAsync(aggr, 0, aggr_b, stream);

    if (csr_ok) {
        hipMemsetAsync(counts, 0, (size_t)N * 4, stream);
        k_hist   <<<grid_E, 256, 0, stream>>>(ei, flag, counts, E);
        k_scan1  <<<nblk_scan, 256, 0, stream>>>(counts, offs, parts, N);
        k_scan2  <<<1, 256, 0, stream>>>(parts, nblk_scan);
        k_scan3  <<<grid_Nt, 256, 0, stream>>>(offs, parts, cursor, N);
        k_scatter<<<grid_E, 256, 0, stream>>>(ei, flag, cursor, csr_sr, E);
        k_edge_srt<<<grid_e, 256, 0, stream>>>(
            AB, pos, csr_sr, W2, b2, W1 + 256 * 128, aggr, E, ng_edges);
    } else {
        k_edge_fb<<<grid_e, 256, 0, stream>>>(AB, pos, ei, flag, W2, b2,
                                              W1 + 256 * 128, aggr, E, ng_edges);
    }

    k_node2<<<grid_n, 256, 0, stream>>>(x, aggr, U1, c1, u, N, ng_nodes);
    k_node3<<<grid_n, 256, 0, stream>>>(u, U2, c2, (float*)d_out, N, ng_nodes);
}